// Round 11
// baseline (960.928 us; speedup 1.0000x reference)
//
#include <hip/hip_runtime.h>
#include <hip/hip_cooperative_groups.h>
#include <math.h>

namespace cg = cooperative_groups;

#define NB 8
#define NN 10000
#define NE 160000
#define FD 64
#define BN (NB * NN)              // 80000
#define TOTE (NB * NE)            // 1280000
#define EPB 10000                 // edges per count chunk
#define BPG 16                    // chunks per graph
#define NPA (NB * BPG)            // 128 count chunks
#define WTS 68                    // padded Wt stride
#define MAXG 1024                 // cooperative grid cap (4 blocks/CU @ 40KB LDS)

// ======================= device helpers (mega phases) =======================

template <int RELU, int SCALE>
__device__ __forceinline__ void lin_phase(const float* __restrict__ hin,
                                          const float* __restrict__ W,
                                          const float* __restrict__ bias,
                                          const float* __restrict__ dinv,
                                          float* __restrict__ tout,
                                          float* Wt, float* bsh, int GB) {
    for (int b = blockIdx.x; b < 320; b += GB) {
        for (int idx = threadIdx.x; idx < FD * FD; idx += 256) {
            int j = idx >> 6, k = idx & 63;
            Wt[k * WTS + j] = W[idx];
        }
        if (threadIdx.x < FD) bsh[threadIdx.x] = bias[threadIdx.x];
        __syncthreads();
        int g = b & 7, i = b >> 3;
        int nl = i * 256 + (int)threadIdx.x;
        if (nl < NN) {
            int n = g * NN + nl;
            float acc[FD];
#pragma unroll
            for (int j = 0; j < FD; j++) acc[j] = bsh[j];
            const float4* hp = (const float4*)(hin + (size_t)n * FD);
#pragma unroll
            for (int k4 = 0; k4 < 16; k4++) {
                float4 hv = hp[k4];
                if (RELU) {
                    hv.x = fmaxf(hv.x, 0.f); hv.y = fmaxf(hv.y, 0.f);
                    hv.z = fmaxf(hv.z, 0.f); hv.w = fmaxf(hv.w, 0.f);
                }
                float hk[4] = {hv.x, hv.y, hv.z, hv.w};
#pragma unroll
                for (int kk = 0; kk < 4; kk++) {
                    const float4* wr = (const float4*)(&Wt[(k4 * 4 + kk) * WTS]);
                    float h = hk[kk];
#pragma unroll
                    for (int j4 = 0; j4 < 16; j4++) {
                        float4 w = wr[j4];
                        acc[4 * j4 + 0] += h * w.x;
                        acc[4 * j4 + 1] += h * w.y;
                        acc[4 * j4 + 2] += h * w.z;
                        acc[4 * j4 + 3] += h * w.w;
                    }
                }
            }
            float dn = SCALE ? dinv[n] : 1.0f;
            float4* op = (float4*)(tout + (size_t)n * FD);
#pragma unroll
            for (int j4 = 0; j4 < 16; j4++)
                op[j4] = make_float4(dn * acc[4 * j4], dn * acc[4 * j4 + 1],
                                     dn * acc[4 * j4 + 2], dn * acc[4 * j4 + 3]);
        }
        __syncthreads();
    }
}

// WITHNORM=1: t unscaled, apply dinv[c] per edge (metadata superchunk gathers it).
template <int WITHNORM>
__device__ __forceinline__ void agg_phase(const float* __restrict__ t,
                                          const int* __restrict__ row_start,
                                          const int* __restrict__ edge_col,
                                          const float* __restrict__ dinv,
                                          float* __restrict__ outp, int GB) {
    int lane = threadIdx.x & 63;
    int wv = threadIdx.x >> 6;
    int eg = lane >> 4, fl = lane & 15;
    for (int wb = blockIdx.x; wb < 1024; wb += GB) {
        int g = wb & 7;
        int wig = (wb >> 3) * 4 + wv;           // 0..511 within graph
        for (int nl = wig; nl < NN; nl += 512) {
            int node = __builtin_amdgcn_readfirstlane(g * NN + nl);
            int p0 = row_start[node];
            int pe = row_start[node + 1];
            float dr = dinv[node];
            float4 acc = make_float4(0.f, 0.f, 0.f, 0.f);
            for (int sb = p0; sb < pe; sb += 64) {
                int pl = sb + lane;
                int col = (pl < pe) ? edge_col[pl] : 0;
                float dc = WITHNORM ? dinv[col] : 0.f;
                int cnt = pe - sb;
                if (cnt > 64) cnt = 64;
                int kmax = (cnt + 3) >> 2;
                for (int k = 0; k < kmax; k++) {
                    int s = k * 4 + eg;
                    int c = __shfl(col, s);
                    float w = WITHNORM ? __shfl(dc, s) : 1.0f;
                    if (s < cnt) {
                        float4 tv = ((const float4*)(t + (size_t)c * FD))[fl];
                        if (WITHNORM) {
                            acc.x += w * tv.x; acc.y += w * tv.y;
                            acc.z += w * tv.z; acc.w += w * tv.w;
                        } else {
                            acc.x += tv.x; acc.y += tv.y;
                            acc.z += tv.z; acc.w += tv.w;
                        }
                    }
                }
            }
            acc.x += __shfl_down(acc.x, 32); acc.y += __shfl_down(acc.y, 32);
            acc.z += __shfl_down(acc.z, 32); acc.w += __shfl_down(acc.w, 32);
            acc.x += __shfl_down(acc.x, 16); acc.y += __shfl_down(acc.y, 16);
            acc.z += __shfl_down(acc.z, 16); acc.w += __shfl_down(acc.w, 16);
            if (lane < 16) {
                float4* op = (float4*)(outp + (size_t)node * FD);
                op[fl] = make_float4(dr * acc.x, dr * acc.y, dr * acc.z, dr * acc.w);
            }
        }
    }
}

// ======================= mega kernel (cooperative) =======================
__global__ __launch_bounds__(256, 4) void mega(const int* __restrict__ ei,
                                               const float* __restrict__ x,
                                               const float* __restrict__ W1,
                                               const float* __restrict__ b1,
                                               const float* __restrict__ W2,
                                               const float* __restrict__ b2,
                                               const float* __restrict__ W3,
                                               const float* __restrict__ b3,
                                               int* __restrict__ rank,
                                               int* __restrict__ cnt,
                                               int* __restrict__ row_start,
                                               float* __restrict__ dinv,
                                               int* __restrict__ edge_col,
                                               float* __restrict__ A,
                                               float* __restrict__ Bb,
                                               float* __restrict__ outp,
                                               int* __restrict__ blocksum) {
    cg::grid_group grid = cg::this_grid();
    __shared__ __align__(16) int shU[NN];   // 40 KB union: hist | Wt+bsh
    __shared__ int wsums[16];
    const int tid = threadIdx.x;
    const int lane = tid & 63;
    const int wv = tid >> 6;
    const int GB = gridDim.x;
    float* WtF = (float*)shU;
    float* bshF = WtF + WTS * FD;           // 4352..4415 floats, inside shU

    // ---- P0: count (chunks 0..127) + lin1 UNSCALED (chunks 128..447) ----
    for (int chunk = blockIdx.x; chunk < 128 + 320; chunk += GB) {
        if (chunk < 128) {
            int g = chunk >> 4, j = chunk & 15;
            for (int i = tid; i < NN; i += 256) shU[i] = 0;
            __syncthreads();
            int base = g * NE + j * EPB;
            for (int i = tid; i < EPB; i += 256) {
                int e = base + i;
                int r = ei[2 * e];
                rank[e] = atomicAdd(&shU[r], 1);
            }
            __syncthreads();
            int* cp = cnt + (size_t)chunk * NN;
            for (int i = tid; i < NN; i += 256) cp[i] = shU[i];
            __syncthreads();
        } else {
            int b = chunk - 128;
            int g = b & 7, i = b >> 3;
            for (int idx = tid; idx < FD * FD; idx += 256) {
                int jj = idx >> 6, k = idx & 63;
                WtF[k * WTS + jj] = W1[idx];
            }
            if (tid < FD) bshF[tid] = b1[tid];
            __syncthreads();
            int nl = i * 256 + tid;
            if (nl < NN) {
                int n = g * NN + nl;
                float acc[FD];
#pragma unroll
                for (int j = 0; j < FD; j++) acc[j] = bshF[j];
                const float4* hp = (const float4*)(x + (size_t)n * FD);
#pragma unroll
                for (int k4 = 0; k4 < 16; k4++) {
                    float4 hv = hp[k4];
                    float hk[4] = {hv.x, hv.y, hv.z, hv.w};
#pragma unroll
                    for (int kk = 0; kk < 4; kk++) {
                        const float4* wr = (const float4*)(&WtF[(k4 * 4 + kk) * WTS]);
                        float h = hk[kk];
#pragma unroll
                        for (int j4 = 0; j4 < 16; j4++) {
                            float4 w = wr[j4];
                            acc[4 * j4 + 0] += h * w.x;
                            acc[4 * j4 + 1] += h * w.y;
                            acc[4 * j4 + 2] += h * w.z;
                            acc[4 * j4 + 3] += h * w.w;
                        }
                    }
                }
                float4* op = (float4*)(A + (size_t)n * FD);
#pragma unroll
                for (int j4 = 0; j4 < 16; j4++)
                    op[j4] = make_float4(acc[4 * j4], acc[4 * j4 + 1],
                                         acc[4 * j4 + 2], acc[4 * j4 + 3]);
            }
            __syncthreads();
        }
    }
    grid.sync();

    // ---- P1a: per-node deg + chunk prefix; per-segment sums ----
    // 320 segments: seg-block wb -> graph g=wb/40, seg=wb%40, nodes [seg*250,+250)
    for (int wb = blockIdx.x; wb < 320; wb += GB) {
        int g = wb / 40, seg = wb % 40;
        int iLoc = seg * 250 + tid;
        int d = 0;
        if (tid < 250) {
            int* cp = cnt + (size_t)g * BPG * NN + iLoc;
            int run = 0;
#pragma unroll
            for (int j = 0; j < BPG; j++) {
                int v = cp[(size_t)j * NN];
                cp[(size_t)j * NN] = run;       // within-node chunk prefix
                run += v;
            }
            d = run;
            row_start[g * NN + iLoc] = d;       // temp: deg
        }
        int s = d;
#pragma unroll
        for (int off = 32; off > 0; off >>= 1) s += __shfl_down(s, off);
        if (lane == 0) wsums[wv] = s;
        __syncthreads();
        if (tid == 0) blocksum[wb] = wsums[0] + wsums[1] + wsums[2] + wsums[3];
        __syncthreads();
    }
    grid.sync();

    // ---- P1c: segment base + intra-segment scan -> row_start/start2/dinv ----
    for (int wb = blockIdx.x; wb < 320; wb += GB) {
        int g = wb / 40, seg = wb % 40;
        int v = (lane < seg) ? blocksum[g * 40 + lane] : 0;
#pragma unroll
        for (int off = 32; off > 0; off >>= 1) v += __shfl_down(v, off);
        int base = __shfl(v, 0);
        int iLoc = seg * 250 + tid;
        int d = (tid < 250) ? row_start[g * NN + iLoc] : 0;
        int xs = d;
#pragma unroll
        for (int off = 1; off < 64; off <<= 1) {
            int y = __shfl_up(xs, off);
            if (lane >= off) xs += y;
        }
        if (lane == 63) wsums[wv] = xs;
        __syncthreads();
        int add = 0;
        for (int w = 0; w < wv; w++) add += wsums[w];
        if (tid < 250) {
            int abs0 = g * NE + base + add + (xs - d);
            row_start[g * NN + iLoc] = abs0;
            dinv[g * NN + iLoc] = (d > 0) ? (1.0f / sqrtf((float)d)) : 0.0f;
            int* cp = cnt + (size_t)g * BPG * NN + iLoc;
#pragma unroll
            for (int j = 0; j < BPG; j++) cp[(size_t)j * NN] += abs0;  // -> start2
        }
        __syncthreads();
    }
    if (blockIdx.x == 0 && tid == 0) row_start[BN] = TOTE;
    grid.sync();

    // ---- P2: fill (random scatter; L2-RMW-bound ~45us, accepted) ----
    for (int wb = blockIdx.x; wb < 1024; wb += GB) {
        int g = wb & 7, j = wb >> 3;            // j 0..127, 1250 edges
        int lo = j * 1250, hi = lo + 1250;
        for (int i = lo + tid; i < hi; i += 256) {
            int e = g * NE + i;
            int2 rc = ((const int2*)ei)[e];
            int rk = rank[e];
            int jj = i / EPB;
            int pos = cnt[((size_t)(g * BPG + jj)) * NN + rc.x] + rk;
            edge_col[pos] = g * NN + rc.y;
        }
    }
    grid.sync();

    // ---- P3: h1 = agg_norm(A) -> Bb ----
    agg_phase<1>(A, row_start, edge_col, dinv, Bb, GB);
    grid.sync();
    // ---- P4: A = dinv*(relu(h1)@W2^T + b2) ----
    lin_phase<1, 1>(Bb, W2, b2, dinv, A, WtF, bshF, GB);
    grid.sync();
    // ---- P5: h2 = agg(A) -> Bb ----
    agg_phase<0>(A, row_start, edge_col, dinv, Bb, GB);
    grid.sync();
    // ---- P6: A = dinv*(relu(h2)@W3^T + b3) ----
    lin_phase<1, 1>(Bb, W3, b3, dinv, A, WtF, bshF, GB);
    grid.sync();
    // ---- P7: out = agg(A) ----
    agg_phase<0>(A, row_start, edge_col, dinv, outp, GB);
}

// ======================= fallback: proven R10 path =======================
__global__ __launch_bounds__(256) void fb_count(const int* __restrict__ ei,
                                                int* __restrict__ rank,
                                                int* __restrict__ cnt) {
    __shared__ int hist[NN];
    for (int i = threadIdx.x; i < NN; i += 256) hist[i] = 0;
    __syncthreads();
    int g = blockIdx.x >> 4, j = blockIdx.x & 15;
    int base = g * NE + j * EPB;
    for (int i = threadIdx.x; i < EPB; i += 256) {
        int e = base + i;
        rank[e] = atomicAdd(&hist[ei[2 * e]], 1);
    }
    __syncthreads();
    int* cp = cnt + (size_t)blockIdx.x * NN;
    for (int i = threadIdx.x; i < NN; i += 256) cp[i] = hist[i];
}

__global__ __launch_bounds__(1024) void fb_scan(int* __restrict__ cnt,
                                                int* __restrict__ row_start,
                                                float* __restrict__ dinv) {
    __shared__ int wsums[16];
    __shared__ int carry_s;
    const int g = blockIdx.x;
    const int tid = threadIdx.x;
    const int lane = tid & 63;
    const int wv = tid >> 6;
    if (tid == 0) carry_s = 0;
    if (g == 0 && tid == 0) row_start[BN] = TOTE;
    __syncthreads();
    for (int base = 0; base < NN; base += 1024) {
        int i = base + tid;
        int d = 0;
        int* cp = cnt + (size_t)g * BPG * NN + i;
        if (i < NN) {
            int run = 0;
#pragma unroll
            for (int j = 0; j < BPG; j++) {
                int v = cp[(size_t)j * NN];
                cp[(size_t)j * NN] = run;
                run += v;
            }
            d = run;
        }
        int x = d;
#pragma unroll
        for (int off = 1; off < 64; off <<= 1) {
            int y = __shfl_up(x, off);
            if (lane >= off) x += y;
        }
        if (lane == 63) wsums[wv] = x;
        __syncthreads();
        if (wv == 0 && lane < 16) {
            int s = wsums[lane];
#pragma unroll
            for (int off = 1; off < 16; off <<= 1) {
                int y = __shfl_up(s, off, 16);
                if (lane >= off) s += y;
            }
            wsums[lane] = s;
        }
        __syncthreads();
        int excl = carry_s + ((wv > 0) ? wsums[wv - 1] : 0) + (x - d);
        if (i < NN) {
            int abs0 = g * NE + excl;
            row_start[g * NN + i] = abs0;
            dinv[g * NN + i] = (d > 0) ? (1.0f / sqrtf((float)d)) : 0.0f;
#pragma unroll
            for (int j = 0; j < BPG; j++) cp[(size_t)j * NN] += abs0;
        }
        __syncthreads();
        if (tid == 0) carry_s += wsums[15];
        __syncthreads();
    }
}

__global__ __launch_bounds__(256) void fb_fill(const int* __restrict__ ei,
                                               const int* __restrict__ rank,
                                               const int* __restrict__ start2,
                                               int* __restrict__ edge_col) {
    int g = blockIdx.x & 7;
    int j = blockIdx.x >> 3;
    int idx = j * 256 + threadIdx.x;
    int e = g * NE + idx;
    int2 rc = ((const int2*)ei)[e];
    int jj = idx / EPB;
    int pos = start2[((size_t)(g * BPG + jj)) * NN + rc.x] + rank[e];
    edge_col[pos] = g * NN + rc.y;
}

template <int RELU, int SCALE>
__global__ __launch_bounds__(256) void fb_linear(const float* __restrict__ hin,
                                                 const float* __restrict__ W,
                                                 const float* __restrict__ bias,
                                                 const float* __restrict__ dinv,
                                                 float* __restrict__ tout) {
    __shared__ __align__(16) float Wt[WTS * FD];
    __shared__ float bsh[FD];
    lin_phase<RELU, SCALE>(hin, W, bias, dinv, tout, Wt, bsh, 1 << 30);
}

template <int WITHNORM>
__global__ __launch_bounds__(256) void fb_agg(const float* __restrict__ t,
                                              const int* __restrict__ row_start,
                                              const int* __restrict__ edge_col,
                                              const float* __restrict__ dinv,
                                              float* __restrict__ outp) {
    agg_phase<WITHNORM>(t, row_start, edge_col, dinv, outp, 1 << 30);
}

// ======================= launch =======================
extern "C" void kernel_launch(void* const* d_in, const int* in_sizes, int n_in,
                              void* d_out, int out_size, void* d_ws, size_t ws_size,
                              hipStream_t stream) {
    const int*   ei = (const int*)d_in[1];
    const float* x  = (const float*)d_in[0];
    const float* W1 = (const float*)d_in[2];
    const float* b1 = (const float*)d_in[3];
    const float* W2 = (const float*)d_in[4];
    const float* b2 = (const float*)d_in[5];
    const float* W3 = (const float*)d_in[6];
    const float* b3 = (const float*)d_in[7];
    float* outp = (float*)d_out;

    char* ws = (char*)d_ws;
    size_t off = 0;
    float* A        = (float*)(ws + off); off += (size_t)BN * FD * 4;   // 20.48 MB
    float* Bb       = (float*)(ws + off); off += (size_t)BN * FD * 4;   // 20.48 MB
    int*   edge_col = (int*)(ws + off);   off += (size_t)TOTE * 4;      // 5.12 MB
    int*   row_start= (int*)(ws + off);   off += (size_t)(BN + 1) * 4;
    float* dinv     = (float*)(ws + off); off += (size_t)BN * 4;
    int*   blocksum = (int*)(ws + off);   off += 320 * 4;
    // rank + cnt alias Bb (first written at P3/agg1, after last rank/cnt read)
    int*   rank     = (int*)Bb;
    int*   cnt      = (int*)Bb + (size_t)TOTE;

    // occupancy-safe cooperative grid (deterministic per environment)
    int maxPerCU = 0;
    hipError_t qerr = hipOccupancyMaxActiveBlocksPerMultiprocessor(
        &maxPerCU, (const void*)mega, 256, 0);
    int GB = (qerr == hipSuccess && maxPerCU > 0) ? maxPerCU * 256 : MAXG;
    if (GB > MAXG) GB = MAXG;

    void* kargs[] = {(void*)&ei, (void*)&x, (void*)&W1, (void*)&b1, (void*)&W2,
                     (void*)&b2, (void*)&W3, (void*)&b3, (void*)&rank, (void*)&cnt,
                     (void*)&row_start, (void*)&dinv, (void*)&edge_col, (void*)&A,
                     (void*)&Bb, (void*)&outp, (void*)&blocksum};
    hipError_t lerr = hipLaunchCooperativeKernel((void*)mega, dim3(GB), dim3(256),
                                                 kargs, 0, stream);
    if (lerr != hipSuccess) {
        // fallback: proven R10 multi-dispatch path (same math: lin1 unscaled +
        // agg1 with per-edge dinv[c])
        fb_count<<<NPA, 256, 0, stream>>>(ei, rank, cnt);
        fb_scan<<<NB, 1024, 0, stream>>>(cnt, row_start, dinv);
        fb_fill<<<NB * (NE / 256), 256, 0, stream>>>(ei, rank, cnt, edge_col);
        fb_linear<0, 0><<<320, 256, 0, stream>>>(x, W1, b1, dinv, A);
        fb_agg<1><<<1024, 256, 0, stream>>>(A, row_start, edge_col, dinv, Bb);
        fb_linear<1, 1><<<320, 256, 0, stream>>>(Bb, W2, b2, dinv, A);
        fb_agg<0><<<1024, 256, 0, stream>>>(A, row_start, edge_col, dinv, Bb);
        fb_linear<1, 1><<<320, 256, 0, stream>>>(Bb, W3, b3, dinv, A);
        fb_agg<0><<<1024, 256, 0, stream>>>(A, row_start, edge_col, dinv, outp);
    }
}

// Round 12
// 298.319 us; speedup vs baseline: 3.2211x; 3.2211x over previous
//
#include <hip/hip_runtime.h>
#include <math.h>

#define NB 8
#define NN 10000
#define NE 160000
#define FD 64
#define BN (NB * NN)              // 80000
#define TOTE (NB * NE)            // 1280000
#define EPB 10000                 // edges per count chunk
#define BPG (NE / EPB)            // 16 chunks per graph
#define NPA (NB * BPG)            // 128 count blocks
#define FILLB 1000                // fill blocks: 125/graph, 5 edges/thread
#define LINB 320                  // linear blocks (40 per graph)
#define WTS 68                    // padded Wt stride
#define AGGB 5000                 // agg blocks: 625/graph, 4 waves x 4 nodes = 16 nodes/block

// ---------- 1: LDS histogram count + per-edge local rank (128 blocks) ----------
__global__ __launch_bounds__(256) void k_count_lds(const int* __restrict__ ei,
                                                   int* __restrict__ rank,
                                                   int* __restrict__ cnt) {
    __shared__ int hist[NN];  // 40 KB
    for (int i = threadIdx.x; i < NN; i += 256) hist[i] = 0;
    __syncthreads();
    int g = blockIdx.x >> 4;
    int j = blockIdx.x & 15;
    int base = g * NE + j * EPB;
    for (int i = threadIdx.x; i < EPB; i += 256) {
        int e = base + i;
        int r = ei[2 * e];
        rank[e] = atomicAdd(&hist[r], 1);
    }
    __syncthreads();
    int* cp = cnt + (size_t)blockIdx.x * NN;
    for (int i = threadIdx.x; i < NN; i += 256) cp[i] = hist[i];
}

// ---------- 2: per-graph scan (8 blocks x 1024) -> row_start, dinv, start2 ----------
__global__ __launch_bounds__(1024) void k_scan_g(int* __restrict__ cnt,
                                                 int* __restrict__ row_start,
                                                 float* __restrict__ dinv) {
    __shared__ int wsums[16];
    __shared__ int carry_s;
    const int g = blockIdx.x;
    const int tid = threadIdx.x;
    const int lane = tid & 63;
    const int wv = tid >> 6;
    if (tid == 0) carry_s = 0;
    if (g == 0 && tid == 0) row_start[BN] = TOTE;
    __syncthreads();
    for (int base = 0; base < NN; base += 1024) {
        int i = base + tid;
        int d = 0;
        int* cp = cnt + ((size_t)g * BPG) * NN + i;
        if (i < NN) {
            int run = 0;
#pragma unroll
            for (int j = 0; j < BPG; j++) {
                int v = cp[(size_t)j * NN];
                cp[(size_t)j * NN] = run;     // within-node chunk prefix
                run += v;
            }
            d = run;
        }
        int x = d;
#pragma unroll
        for (int off = 1; off < 64; off <<= 1) {
            int y = __shfl_up(x, off);
            if (lane >= off) x += y;
        }
        if (lane == 63) wsums[wv] = x;
        __syncthreads();
        if (wv == 0 && lane < 16) {
            int s = wsums[lane];
#pragma unroll
            for (int off = 1; off < 16; off <<= 1) {
                int y = __shfl_up(s, off, 16);
                if (lane >= off) s += y;
            }
            wsums[lane] = s;
        }
        __syncthreads();
        int excl = carry_s + ((wv > 0) ? wsums[wv - 1] : 0) + (x - d);
        if (i < NN) {
            int abs0 = g * NE + excl;
            row_start[g * NN + i] = abs0;
            dinv[g * NN + i] = (d > 0) ? (1.0f / sqrtf((float)d)) : 0.0f;
#pragma unroll
            for (int j = 0; j < BPG; j++) cp[(size_t)j * NN] += abs0;  // -> start2
        }
        __syncthreads();
        if (tid == 0) carry_s += wsums[15];
        __syncthreads();
    }
}

// ---------- 3: fill CSR col-only (blocks 0..999, 5 edges/thread) + linear1 ----------
__global__ __launch_bounds__(256) void k_fill_lin(const int* __restrict__ ei,
                                                  const int* __restrict__ rank,
                                                  const int* __restrict__ start2,
                                                  int* __restrict__ edge_col,
                                                  const float* __restrict__ x,
                                                  const float* __restrict__ W1,
                                                  const float* __restrict__ b1,
                                                  const float* __restrict__ dinv,
                                                  float* __restrict__ t1) {
    __shared__ __align__(16) float Wt[WTS * FD];
    __shared__ float bsh[FD];
    if (blockIdx.x < FILLB) {
        int g = blockIdx.x & 7;
        int j = blockIdx.x >> 3;                 // 0..124
        int base = j * 1280 + (int)threadIdx.x;
        int2 rc[5];
        int rk[5];
        int idxs[5];
#pragma unroll
        for (int u = 0; u < 5; u++) {
            int idx = base + u * 256;
            idxs[u] = idx;
            int e = g * NE + idx;
            rc[u] = ((const int2*)ei)[e];
            rk[u] = rank[g * NE + idx];
        }
        int pos[5];
#pragma unroll
        for (int u = 0; u < 5; u++) {
            int jj = idxs[u] / EPB;
            pos[u] = start2[((size_t)(g * BPG + jj)) * NN + rc[u].x] + rk[u];
        }
#pragma unroll
        for (int u = 0; u < 5; u++)
            edge_col[pos[u]] = g * NN + rc[u].y;
    } else {
        // linear1: t1 = dinv[n] * (x @ W1^T + b1)
        for (int idx = threadIdx.x; idx < FD * FD; idx += 256) {
            int j = idx >> 6, k = idx & 63;
            Wt[k * WTS + j] = W1[idx];
        }
        if (threadIdx.x < FD) bsh[threadIdx.x] = b1[threadIdx.x];
        __syncthreads();

        int b = blockIdx.x - FILLB;
        int g = b & 7;
        int i = b >> 3;
        int nl = i * 256 + (int)threadIdx.x;
        if (nl >= NN) return;
        int n = g * NN + nl;

        float acc[FD];
#pragma unroll
        for (int j = 0; j < FD; j++) acc[j] = bsh[j];

        const float4* hp = (const float4*)(x + (size_t)n * FD);
#pragma unroll
        for (int k4 = 0; k4 < 16; k4++) {
            float4 hv = hp[k4];
            float hk[4] = {hv.x, hv.y, hv.z, hv.w};
#pragma unroll
            for (int kk = 0; kk < 4; kk++) {
                const float4* wr = (const float4*)(&Wt[(k4 * 4 + kk) * WTS]);
                float h = hk[kk];
#pragma unroll
                for (int j4 = 0; j4 < 16; j4++) {
                    float4 w = wr[j4];
                    acc[4 * j4 + 0] += h * w.x;
                    acc[4 * j4 + 1] += h * w.y;
                    acc[4 * j4 + 2] += h * w.z;
                    acc[4 * j4 + 3] += h * w.w;
                }
            }
        }
        float dn = dinv[n];
        float4* op = (float4*)(t1 + (size_t)n * FD);
#pragma unroll
        for (int j4 = 0; j4 < 16; j4++)
            op[j4] = make_float4(dn * acc[4 * j4], dn * acc[4 * j4 + 1],
                                 dn * acc[4 * j4 + 2], dn * acc[4 * j4 + 3]);
    }
}

// ---------- linear (layers 2,3): t[n] = dinv[n] * (relu(h[n]) @ W^T + b) ----------
__global__ __launch_bounds__(256) void k_linear(const float* __restrict__ hin,
                                                const float* __restrict__ W,
                                                const float* __restrict__ bias,
                                                const float* __restrict__ dinv,
                                                float* __restrict__ tout) {
    __shared__ __align__(16) float Wt[WTS * FD];
    __shared__ float bsh[FD];
    for (int idx = threadIdx.x; idx < FD * FD; idx += 256) {
        int j = idx >> 6, k = idx & 63;
        Wt[k * WTS + j] = W[idx];
    }
    if (threadIdx.x < FD) bsh[threadIdx.x] = bias[threadIdx.x];
    __syncthreads();

    int b = blockIdx.x;
    int g = b & 7;
    int i = b >> 3;
    int nl = i * 256 + (int)threadIdx.x;
    if (nl >= NN) return;
    int n = g * NN + nl;

    float acc[FD];
#pragma unroll
    for (int j = 0; j < FD; j++) acc[j] = bsh[j];

    const float4* hp = (const float4*)(hin + (size_t)n * FD);
#pragma unroll
    for (int k4 = 0; k4 < 16; k4++) {
        float4 hv = hp[k4];
        hv.x = fmaxf(hv.x, 0.f);
        hv.y = fmaxf(hv.y, 0.f);
        hv.z = fmaxf(hv.z, 0.f);
        hv.w = fmaxf(hv.w, 0.f);
        float hk[4] = {hv.x, hv.y, hv.z, hv.w};
#pragma unroll
        for (int kk = 0; kk < 4; kk++) {
            const float4* wr = (const float4*)(&Wt[(k4 * 4 + kk) * WTS]);
            float h = hk[kk];
#pragma unroll
            for (int j4 = 0; j4 < 16; j4++) {
                float4 w = wr[j4];
                acc[4 * j4 + 0] += h * w.x;
                acc[4 * j4 + 1] += h * w.y;
                acc[4 * j4 + 2] += h * w.z;
                acc[4 * j4 + 3] += h * w.w;
            }
        }
    }
    float dn = dinv[n];
    float4* op = (float4*)(tout + (size_t)n * FD);
#pragma unroll
    for (int j4 = 0; j4 < 16; j4++)
        op[j4] = make_float4(dn * acc[4 * j4], dn * acc[4 * j4 + 1],
                             dn * acc[4 * j4 + 2], dn * acc[4 * j4 + 3]);
}

// ---------- aggregate: 4 NODES PER WAVE (latency-hiding ILP) ----------
// out[r] = dinv[r] * sum_e t[col[e]] (t pre-scaled by dinv).
// 4 independent dep-chains per wave: 4 col superchunk loads + up to 16
// t-gathers in flight. Consecutive nodes -> contiguous CSR ranges (shared
// lines). XCD swizzle g = blk&7 keeps graph g's t slice in one XCD L2.
__global__ __launch_bounds__(256) void k_agg(const float* __restrict__ t,
                                             const int* __restrict__ row_start,
                                             const int* __restrict__ edge_col,
                                             const float* __restrict__ dinv,
                                             float* __restrict__ out) {
    int g = blockIdx.x & 7;
    int i = blockIdx.x >> 3;                          // 0..624
    int lane = threadIdx.x & 63;
    int eg = lane >> 4;
    int fl = lane & 15;
    int node0 = __builtin_amdgcn_readfirstlane(
        g * NN + i * 16 + ((int)threadIdx.x >> 6) * 4);

    int p[5];
#pragma unroll
    for (int u = 0; u < 5; u++) p[u] = row_start[node0 + u];
    float dr[4];
#pragma unroll
    for (int u = 0; u < 4; u++) dr[u] = dinv[node0 + u];

    // superchunk col loads: 4 independent
    int cols[4];
    int cnt[4];
#pragma unroll
    for (int u = 0; u < 4; u++) {
        int pl = p[u] + lane;
        cols[u] = (pl < p[u + 1]) ? edge_col[pl] : 0;
        int c = p[u + 1] - p[u];
        cnt[u] = (c > 64) ? 64 : c;
    }
    int kmax = 0;
#pragma unroll
    for (int u = 0; u < 4; u++) {
        int km = (cnt[u] + 3) >> 2;
        kmax = (km > kmax) ? km : kmax;
    }

    float4 acc[4];
#pragma unroll
    for (int u = 0; u < 4; u++) acc[u] = make_float4(0.f, 0.f, 0.f, 0.f);

    for (int k = 0; k < kmax; k++) {
        int s = k * 4 + eg;
#pragma unroll
        for (int u = 0; u < 4; u++) {
            int c = __shfl(cols[u], s);
            if (s < cnt[u]) {
                float4 tv = ((const float4*)(t + (size_t)c * FD))[fl];
                acc[u].x += tv.x;
                acc[u].y += tv.y;
                acc[u].z += tv.z;
                acc[u].w += tv.w;
            }
        }
    }
    // rare overflow (deg > 64): per-edge cleanup, 16 lanes per eg share addr
#pragma unroll
    for (int u = 0; u < 4; u++) {
        for (int q = p[u] + 64 + eg; q < p[u + 1]; q += 4) {
            int c = edge_col[q];
            float4 tv = ((const float4*)(t + (size_t)c * FD))[fl];
            acc[u].x += tv.x;
            acc[u].y += tv.y;
            acc[u].z += tv.z;
            acc[u].w += tv.w;
        }
    }
#pragma unroll
    for (int u = 0; u < 4; u++) {
        acc[u].x += __shfl_down(acc[u].x, 32); acc[u].y += __shfl_down(acc[u].y, 32);
        acc[u].z += __shfl_down(acc[u].z, 32); acc[u].w += __shfl_down(acc[u].w, 32);
        acc[u].x += __shfl_down(acc[u].x, 16); acc[u].y += __shfl_down(acc[u].y, 16);
        acc[u].z += __shfl_down(acc[u].z, 16); acc[u].w += __shfl_down(acc[u].w, 16);
    }
    if (lane < 16) {
#pragma unroll
        for (int u = 0; u < 4; u++) {
            float4* op = (float4*)(out + (size_t)(node0 + u) * FD);
            op[fl] = make_float4(dr[u] * acc[u].x, dr[u] * acc[u].y,
                                 dr[u] * acc[u].z, dr[u] * acc[u].w);
        }
    }
}

extern "C" void kernel_launch(void* const* d_in, const int* in_sizes, int n_in,
                              void* d_out, int out_size, void* d_ws, size_t ws_size,
                              hipStream_t stream) {
    const float* x  = (const float*)d_in[0];
    const int*   ei = (const int*)d_in[1];
    const float* W1 = (const float*)d_in[2];
    const float* b1 = (const float*)d_in[3];
    const float* W2 = (const float*)d_in[4];
    const float* b2 = (const float*)d_in[5];
    const float* W3 = (const float*)d_in[6];
    const float* b3 = (const float*)d_in[7];
    float* out = (float*)d_out;

    char* ws = (char*)d_ws;
    size_t off = 0;
    float* A        = (float*)(ws + off); off += (size_t)BN * FD * 4;     // 20.48 MB
    float* Bb       = (float*)(ws + off); off += (size_t)BN * FD * 4;     // 20.48 MB
    int*   edge_col = (int*)(ws + off);   off += (size_t)TOTE * 4;        // 5.12 MB
    int*   row_start= (int*)(ws + off);   off += (size_t)(BN + 1) * 4;
    float* dinv     = (float*)(ws + off); off += (size_t)BN * 4;
    // rank + cnt/start2 alias Bb (first written by agg1, after fill's last read)
    int*   rank     = (int*)Bb;
    int*   cnt      = (int*)Bb + (size_t)TOTE;

    k_count_lds<<<NPA, 256, 0, stream>>>(ei, rank, cnt);
    k_scan_g<<<NB, 1024, 0, stream>>>(cnt, row_start, dinv);
    k_fill_lin<<<FILLB + LINB, 256, 0, stream>>>(ei, rank, cnt, edge_col,
                                                 x, W1, b1, dinv, A);
    k_agg<<<AGGB, 256, 0, stream>>>(A, row_start, edge_col, dinv, Bb);   // B = h1
    k_linear<<<LINB, 256, 0, stream>>>(Bb, W2, b2, dinv, A);             // A = t2'
    k_agg<<<AGGB, 256, 0, stream>>>(A, row_start, edge_col, dinv, Bb);   // B = h2
    k_linear<<<LINB, 256, 0, stream>>>(Bb, W3, b3, dinv, A);             // A = t3'
    k_agg<<<AGGB, 256, 0, stream>>>(A, row_start, edge_col, dinv, out);  // out = h3
}